// Round 1
// baseline (354.564 us; speedup 1.0000x reference)
//
#include <hip/hip_runtime.h>

#define EPS 1e-15f

// ---------------------------------------------------------------------------
// Helpers
// ---------------------------------------------------------------------------
__device__ __forceinline__ int load_idx(const int* __restrict__ ei, int is64, int pos) {
    // int64 little-endian: value lives in the low 32-bit word
    return is64 ? ei[(size_t)2 * pos] : ei[pos];
}

// Detect whether edge_index arrived as int64 (odd int32 words all zero) or int32.
__global__ void detect_kernel(const int* __restrict__ ei, int* __restrict__ flag) {
    __shared__ int any_odd;
    if (threadIdx.x == 0) any_odd = 0;
    __syncthreads();
    if (ei[2 * threadIdx.x + 1] != 0) atomicOr(&any_odd, 1);
    __syncthreads();
    if (threadIdx.x == 0) *flag = any_odd ? 0 : 1;
}

__global__ void deg_kernel(const int* __restrict__ ei, const int* __restrict__ flag,
                           float* __restrict__ deg, int E) {
    int e = blockIdx.x * 256 + threadIdx.x;
    if (e >= E) return;
    int is64 = *flag;
    int dst = load_idx(ei, is64, E + e);
    atomicAdd(&deg[dst], 1.0f);
}

// ---------------------------------------------------------------------------
// GEMM: Cout[n, c] = sum_k A[n,k] * W(k,c), W = [W1 | W2] concat on columns.
// Block tile TN rows x TC cols, 256 threads, each thread 8 rows x 4 cols.
// ---------------------------------------------------------------------------
template<int K, int TN, int TC, int C1, int C2>
__global__ __launch_bounds__(256) void gemm_cat(
    const float* __restrict__ A, const float* __restrict__ W1,
    const float* __restrict__ W2, float* __restrict__ Cout, int nrows) {
    constexpr int NT = TN / 8;
    constexpr int CT = TC / 4;
    static_assert(NT * CT == 256, "bad tile");
    constexpr int COLS = C1 + C2;
    __shared__ float xs[TN][K + 4];

    int row0 = blockIdx.x * TN;
    int col0 = blockIdx.y * TC;

    // Stage A tile (TN x K) into LDS via float4
    constexpr int NV = TN * (K / 4);
    for (int id = threadIdx.x; id < NV; id += 256) {
        int r  = id / (K / 4);
        int k4 = id % (K / 4);
        int gr = row0 + r;
        float4 v = make_float4(0.f, 0.f, 0.f, 0.f);
        if (gr < nrows) v = reinterpret_cast<const float4*>(A + (size_t)gr * K)[k4];
        *reinterpret_cast<float4*>(&xs[r][4 * k4]) = v;
    }
    __syncthreads();

    int ct = threadIdx.x % CT;
    int nt = threadIdx.x / CT;
    int c0 = col0 + ct * 4;

    const float* wp;
    int wstride;
    if (c0 < C1) { wp = W1 + c0;        wstride = C1; }
    else         { wp = W2 + (c0 - C1); wstride = C2; }

    float acc[8][4] = {};
#pragma unroll 4
    for (int k = 0; k < K; ++k) {
        float4 w = *reinterpret_cast<const float4*>(wp + (size_t)k * wstride);
        float xr[8];
#pragma unroll
        for (int i = 0; i < 8; ++i) xr[i] = xs[nt * 8 + i][k];
#pragma unroll
        for (int i = 0; i < 8; ++i) {
            acc[i][0] += xr[i] * w.x;
            acc[i][1] += xr[i] * w.y;
            acc[i][2] += xr[i] * w.z;
            acc[i][3] += xr[i] * w.w;
        }
    }

#pragma unroll
    for (int i = 0; i < 8; ++i) {
        int gr = row0 + nt * 8 + i;
        if (gr < nrows) {
            float4 v = make_float4(acc[i][0], acc[i][1], acc[i][2], acc[i][3]);
            *reinterpret_cast<float4*>(Cout + (size_t)gr * COLS + c0) = v;
        }
    }
}

// ---------------------------------------------------------------------------
// Edge stage 1: 64 lanes per edge (one per m). hw1 is [N,256]: cols 0..191 are
// the K*M (k*64+m) part, cols 192..255 the root part.
// ---------------------------------------------------------------------------
__global__ __launch_bounds__(256) void edge1_kernel(
    const int* __restrict__ ei, const int* __restrict__ flag,
    const float* __restrict__ ea, const float* __restrict__ mu,
    const float* __restrict__ sg, const float* __restrict__ hw1,
    float* __restrict__ agg1, int E) {
    unsigned tid = blockIdx.x * 256u + threadIdx.x;
    unsigned e = tid >> 6;
    int m = tid & 63;
    if (e >= (unsigned)E) return;
    int is64 = *flag;
    int src = load_idx(ei, is64, (int)e);
    int dst = load_idx(ei, is64, E + (int)e);
    float2 a = reinterpret_cast<const float2*>(ea)[e];
    float g[3];
#pragma unroll
    for (int k = 0; k < 3; ++k) {
        float d0 = a.x - mu[2 * k], d1 = a.y - mu[2 * k + 1];
        float s0 = sg[2 * k], s1 = sg[2 * k + 1];
        g[k] = __expf(-0.5f * (d0 * d0 / (EPS + s0 * s0) + d1 * d1 / (EPS + s1 * s1)));
    }
    const float* hr = hw1 + (size_t)src * 256 + m;
    float msg = g[0] * hr[0] + g[1] * hr[64] + g[2] * hr[128];
    atomicAdd(agg1 + (size_t)dst * 64 + m, msg);
}

// Node update 1 (fused mean + root + bias + ELU), in place: agg1 -> h2
__global__ __launch_bounds__(256) void node1_kernel(
    float* __restrict__ agg1, const float* __restrict__ deg,
    const float* __restrict__ hw1, const float* __restrict__ b1, int N) {
    int tid = blockIdx.x * 256 + threadIdx.x;
    if (tid >= N * 64) return;
    int n = tid >> 6, m = tid & 63;
    float d = fmaxf(deg[n], 1.0f);
    float v = agg1[tid] / d + hw1[(size_t)n * 256 + 192 + m] + b1[m];
    agg1[tid] = v > 0.f ? v : expm1f(v);
}

// Edge stage 2: 16 lanes per edge. hw2 is [N,64]: cols 0..47 = k*16+c, 48..63 root.
__global__ __launch_bounds__(256) void edge2_kernel(
    const int* __restrict__ ei, const int* __restrict__ flag,
    const float* __restrict__ ea, const float* __restrict__ mu,
    const float* __restrict__ sg, const float* __restrict__ hw2,
    float* __restrict__ agg2, int E) {
    unsigned tid = blockIdx.x * 256u + threadIdx.x;
    unsigned e = tid >> 4;
    int c = tid & 15;
    if (e >= (unsigned)E) return;
    int is64 = *flag;
    int src = load_idx(ei, is64, (int)e);
    int dst = load_idx(ei, is64, E + (int)e);
    float2 a = reinterpret_cast<const float2*>(ea)[e];
    float g[3];
#pragma unroll
    for (int k = 0; k < 3; ++k) {
        float d0 = a.x - mu[2 * k], d1 = a.y - mu[2 * k + 1];
        float s0 = sg[2 * k], s1 = sg[2 * k + 1];
        g[k] = __expf(-0.5f * (d0 * d0 / (EPS + s0 * s0) + d1 * d1 / (EPS + s1 * s1)));
    }
    const float* hr = hw2 + (size_t)src * 64 + c;
    float msg = g[0] * hr[0] + g[1] * hr[16] + g[2] * hr[32];
    atomicAdd(agg2 + (size_t)dst * 16 + c, msg);
}

// Final: mean + root + bias + log_softmax over 16 classes (16-lane shuffle groups)
__global__ __launch_bounds__(256) void final_kernel(
    const float* __restrict__ agg2, const float* __restrict__ deg,
    const float* __restrict__ hw2, const float* __restrict__ b2,
    float* __restrict__ out, int N) {
    int tid = blockIdx.x * 256 + threadIdx.x;
    if (tid >= N * 16) return;
    int n = tid >> 4, c = tid & 15;
    float d = fmaxf(deg[n], 1.0f);
    float v = agg2[tid] / d + hw2[(size_t)n * 64 + 48 + c] + b2[c];
    float mx = v;
#pragma unroll
    for (int off = 8; off >= 1; off >>= 1) mx = fmaxf(mx, __shfl_xor(mx, off, 16));
    float s = __expf(v - mx);
#pragma unroll
    for (int off = 8; off >= 1; off >>= 1) s += __shfl_xor(s, off, 16);
    out[tid] = v - mx - __logf(s);
}

// ---------------------------------------------------------------------------
extern "C" void kernel_launch(void* const* d_in, const int* in_sizes, int n_in,
                              void* d_out, int out_size, void* d_ws, size_t ws_size,
                              hipStream_t stream) {
    const float* x   = (const float*)d_in[0];
    const int*   ei  = (const int*)d_in[1];
    const float* ea  = (const float*)d_in[2];
    const float* g1  = (const float*)d_in[3];
    const float* mu1 = (const float*)d_in[4];
    const float* sg1 = (const float*)d_in[5];
    const float* r1  = (const float*)d_in[6];
    const float* b1  = (const float*)d_in[7];
    const float* g2  = (const float*)d_in[8];
    const float* mu2 = (const float*)d_in[9];
    const float* sg2 = (const float*)d_in[10];
    const float* r2  = (const float*)d_in[11];
    const float* b2  = (const float*)d_in[12];

    const int N = in_sizes[0] / 128;   // 50000
    const int E = in_sizes[2] / 2;     // 800000

    // Workspace layout (floats)
    float* ws   = (float*)d_ws;
    float* hw1  = ws;                         // N*256  (x @ [g1|root1])
    float* hw2  = hw1 + (size_t)N * 256;      // N*64   (h2 @ [g2|root2])
    float* agg1 = hw2 + (size_t)N * 64;       // N*64   (also reused as h2)
    float* agg2 = agg1 + (size_t)N * 64;      // N*16
    float* deg  = agg2 + (size_t)N * 16;      // N
    int*   flag = (int*)(deg + N);            // 1

    // Zero accumulators (agg1, agg2, deg are contiguous)
    hipMemsetAsync(agg1, 0, sizeof(float) * ((size_t)N * 64 + (size_t)N * 16 + N), stream);

    detect_kernel<<<1, 256, 0, stream>>>(ei, flag);
    deg_kernel<<<(E + 255) / 256, 256, 0, stream>>>(ei, flag, deg, E);

    // Layer 1 GEMM: x [N,128] @ [g1|root1] [128,256] -> hw1
    gemm_cat<128, 64, 128, 192, 64>
        <<<dim3((N + 63) / 64, 2), 256, 0, stream>>>(x, g1, r1, hw1, N);

    edge1_kernel<<<(unsigned)(((size_t)E * 64 + 255) / 256), 256, 0, stream>>>(
        ei, flag, ea, mu1, sg1, hw1, agg1, E);

    node1_kernel<<<(N * 64 + 255) / 256, 256, 0, stream>>>(agg1, deg, hw1, b1, N);

    // Layer 2 GEMM: h2 [N,64] @ [g2|root2] [64,64] -> hw2
    gemm_cat<64, 128, 64, 48, 16>
        <<<dim3((N + 127) / 128, 1), 256, 0, stream>>>(agg1, g2, r2, hw2, N);

    edge2_kernel<<<(unsigned)(((size_t)E * 16 + 255) / 256), 256, 0, stream>>>(
        ei, flag, ea, mu2, sg2, hw2, agg2, E);

    final_kernel<<<(N * 16 + 255) / 256, 256, 0, stream>>>(agg2, deg, hw2, b2,
                                                           (float*)d_out, N);
}

// Round 2
// 300.967 us; speedup vs baseline: 1.1781x; 1.1781x over previous
//
#include <hip/hip_runtime.h>

#define EPS 1e-15f

// ---------------------------------------------------------------------------
// Helpers
// ---------------------------------------------------------------------------
__device__ __forceinline__ int load_idx(const int* __restrict__ ei, int is64, int pos) {
    return is64 ? ei[(size_t)2 * pos] : ei[pos];
}

// Detect whether edge_index arrived as int64 (odd int32 words all zero) or int32.
__global__ void detect_kernel(const int* __restrict__ ei, int* __restrict__ flag) {
    __shared__ int any_odd;
    if (threadIdx.x == 0) any_odd = 0;
    __syncthreads();
    if (ei[2 * threadIdx.x + 1] != 0) atomicOr(&any_odd, 1);
    __syncthreads();
    if (threadIdx.x == 0) *flag = any_odd ? 0 : 1;
}

__global__ void hist_kernel(const int* __restrict__ ei, const int* __restrict__ flag,
                            int* __restrict__ deg, int E) {
    int e = blockIdx.x * 256 + threadIdx.x;
    if (e >= E) return;
    int dst = load_idx(ei, *flag, E + e);
    atomicAdd(&deg[dst], 1);
}

// ---- block-tiled exclusive scan over deg[N] (N <= 256*256) ----
__global__ void scan_part(const int* __restrict__ deg, int* __restrict__ bsum, int N) {
    __shared__ int s[256];
    int i = blockIdx.x * 256 + threadIdx.x;
    s[threadIdx.x] = (i < N) ? deg[i] : 0;
    __syncthreads();
    for (int o = 128; o > 0; o >>= 1) {
        if (threadIdx.x < o) s[threadIdx.x] += s[threadIdx.x + o];
        __syncthreads();
    }
    if (threadIdx.x == 0) bsum[blockIdx.x] = s[0];
}

__global__ void scan_base(int* __restrict__ bsum, int NB, int* __restrict__ rowptrN, int E) {
    __shared__ int s[256];
    int v = (threadIdx.x < NB) ? bsum[threadIdx.x] : 0;
    s[threadIdx.x] = v;
    __syncthreads();
    for (int o = 1; o < 256; o <<= 1) {
        int t = (threadIdx.x >= o) ? s[threadIdx.x - o] : 0;
        __syncthreads();
        s[threadIdx.x] += t;
        __syncthreads();
    }
    if (threadIdx.x < NB) bsum[threadIdx.x] = s[threadIdx.x] - v;  // exclusive
    if (threadIdx.x == 0) *rowptrN = E;                            // rowptr[N]
}

__global__ void scan_final(const int* __restrict__ deg, const int* __restrict__ bsum,
                           int* __restrict__ rowptr, int* __restrict__ cursor, int N) {
    __shared__ int s[256];
    int i = blockIdx.x * 256 + threadIdx.x;
    int v = (i < N) ? deg[i] : 0;
    s[threadIdx.x] = v;
    __syncthreads();
    for (int o = 1; o < 256; o <<= 1) {
        int t = (threadIdx.x >= o) ? s[threadIdx.x - o] : 0;
        __syncthreads();
        s[threadIdx.x] += t;
        __syncthreads();
    }
    int excl = s[threadIdx.x] - v + bsum[blockIdx.x];
    if (i < N) { rowptr[i] = excl; cursor[i] = excl; }
}

// Scatter edges into dst-ordered CSR: rec = {src_bits, g1[0..2]}, eap = edge_attr
__global__ __launch_bounds__(256) void scatter_kernel(
    const int* __restrict__ ei, const int* __restrict__ flag,
    const float2* __restrict__ ea, const float* __restrict__ mu,
    const float* __restrict__ sg, int* __restrict__ cursor,
    float4* __restrict__ rec, float2* __restrict__ eap, int E) {
    int e = blockIdx.x * 256 + threadIdx.x;
    if (e >= E) return;
    int is64 = *flag;
    int src = load_idx(ei, is64, e);
    int dst = load_idx(ei, is64, E + e);
    float2 a = ea[e];
    float g[3];
#pragma unroll
    for (int k = 0; k < 3; ++k) {
        float d0 = a.x - mu[2 * k], d1 = a.y - mu[2 * k + 1];
        float s0 = sg[2 * k], s1 = sg[2 * k + 1];
        g[k] = __expf(-0.5f * (d0 * d0 / (EPS + s0 * s0) + d1 * d1 / (EPS + s1 * s1)));
    }
    int pos = atomicAdd(&cursor[dst], 1);
    rec[pos] = make_float4(__int_as_float(src), g[0], g[1], g[2]);
    eap[pos] = a;
}

// ---------------------------------------------------------------------------
// GEMM: Cout[n, c] = sum_k A[n,k] * W(k,c), W = [W1 | W2] concat on columns.
// ---------------------------------------------------------------------------
template<int K, int TN, int TC, int C1, int C2>
__global__ __launch_bounds__(256) void gemm_cat(
    const float* __restrict__ A, const float* __restrict__ W1,
    const float* __restrict__ W2, float* __restrict__ Cout, int nrows) {
    constexpr int NT = TN / 8;
    constexpr int CT = TC / 4;
    static_assert(NT * CT == 256, "bad tile");
    constexpr int COLS = C1 + C2;
    __shared__ float xs[TN][K + 4];

    int row0 = blockIdx.x * TN;
    int col0 = blockIdx.y * TC;

    constexpr int NV = TN * (K / 4);
    for (int id = threadIdx.x; id < NV; id += 256) {
        int r  = id / (K / 4);
        int k4 = id % (K / 4);
        int gr = row0 + r;
        float4 v = make_float4(0.f, 0.f, 0.f, 0.f);
        if (gr < nrows) v = reinterpret_cast<const float4*>(A + (size_t)gr * K)[k4];
        *reinterpret_cast<float4*>(&xs[r][4 * k4]) = v;
    }
    __syncthreads();

    int ct = threadIdx.x % CT;
    int nt = threadIdx.x / CT;
    int c0 = col0 + ct * 4;

    const float* wp;
    int wstride;
    if (c0 < C1) { wp = W1 + c0;        wstride = C1; }
    else         { wp = W2 + (c0 - C1); wstride = C2; }

    float acc[8][4] = {};
#pragma unroll 4
    for (int k = 0; k < K; ++k) {
        float4 w = *reinterpret_cast<const float4*>(wp + (size_t)k * wstride);
        float xr[8];
#pragma unroll
        for (int i = 0; i < 8; ++i) xr[i] = xs[nt * 8 + i][k];
#pragma unroll
        for (int i = 0; i < 8; ++i) {
            acc[i][0] += xr[i] * w.x;
            acc[i][1] += xr[i] * w.y;
            acc[i][2] += xr[i] * w.z;
            acc[i][3] += xr[i] * w.w;
        }
    }

#pragma unroll
    for (int i = 0; i < 8; ++i) {
        int gr = row0 + nt * 8 + i;
        if (gr < nrows) {
            float4 v = make_float4(acc[i][0], acc[i][1], acc[i][2], acc[i][3]);
            *reinterpret_cast<float4*>(Cout + (size_t)gr * COLS + c0) = v;
        }
    }
}

// ---------------------------------------------------------------------------
// agg1: one 64-lane wave per node. Gather hw1[src] weighted by stored gauss1,
// then fused mean + root + bias + ELU -> h2 [N,64].
// hw1 layout [N,256]: cols k*64+m (k<3), cols 192..255 = root part.
// ---------------------------------------------------------------------------
__global__ __launch_bounds__(256) void agg1_kernel(
    const float4* __restrict__ rec, const int* __restrict__ rowptr,
    const float* __restrict__ hw1, const float* __restrict__ b1,
    float* __restrict__ h2, int N) {
    int node = (blockIdx.x * 256 + threadIdx.x) >> 6;
    int m = threadIdx.x & 63;
    if (node >= N) return;
    int beg = rowptr[node], end = rowptr[node + 1];
    float acc0 = 0.f, acc1 = 0.f;
    int j = beg;
    for (; j + 1 < end; j += 2) {
        float4 r0 = rec[j], r1 = rec[j + 1];
        const float* p0 = hw1 + (size_t)__float_as_int(r0.x) * 256 + m;
        const float* p1 = hw1 + (size_t)__float_as_int(r1.x) * 256 + m;
        acc0 += r0.y * p0[0] + r0.z * p0[64] + r0.w * p0[128];
        acc1 += r1.y * p1[0] + r1.z * p1[64] + r1.w * p1[128];
    }
    if (j < end) {
        float4 r0 = rec[j];
        const float* p0 = hw1 + (size_t)__float_as_int(r0.x) * 256 + m;
        acc0 += r0.y * p0[0] + r0.z * p0[64] + r0.w * p0[128];
    }
    float d = fmaxf((float)(end - beg), 1.0f);
    float v = (acc0 + acc1) / d + hw1[(size_t)node * 256 + 192 + m] + b1[m];
    h2[(size_t)node * 64 + m] = v > 0.f ? v : expm1f(v);
}

// ---------------------------------------------------------------------------
// agg2: one 16-lane group per node. Recompute gauss2 from permuted edge_attr,
// gather hw2[src], fused mean + root + bias + log_softmax -> out [N,16].
// hw2 layout [N,64]: cols k*16+c (k<3), cols 48..63 = root part.
// ---------------------------------------------------------------------------
__global__ __launch_bounds__(256) void agg2_kernel(
    const float* __restrict__ rec, const float2* __restrict__ eap,
    const int* __restrict__ rowptr, const float* __restrict__ hw2,
    const float* __restrict__ mu, const float* __restrict__ sg,
    const float* __restrict__ b2, float* __restrict__ out, int N) {
    int gid = blockIdx.x * 256 + threadIdx.x;
    int n = gid >> 4, c = gid & 15;
    if (n >= N) return;

    float mux[3], muy[3], isx[3], isy[3];
#pragma unroll
    for (int k = 0; k < 3; ++k) {
        mux[k] = mu[2 * k];
        muy[k] = mu[2 * k + 1];
        float s0 = sg[2 * k], s1 = sg[2 * k + 1];
        isx[k] = -0.5f / (EPS + s0 * s0);
        isy[k] = -0.5f / (EPS + s1 * s1);
    }

    int beg = rowptr[n], end = rowptr[n + 1];
    float acc = 0.f;
    for (int j = beg; j < end; ++j) {
        int src = __float_as_int(rec[(size_t)j * 4]);   // rec[j].x only
        float2 a = eap[j];
        float g[3];
#pragma unroll
        for (int k = 0; k < 3; ++k) {
            float d0 = a.x - mux[k], d1 = a.y - muy[k];
            g[k] = __expf(d0 * d0 * isx[k] + d1 * d1 * isy[k]);
        }
        const float* p = hw2 + (size_t)src * 64 + c;
        acc += g[0] * p[0] + g[1] * p[16] + g[2] * p[32];
    }
    float d = fmaxf((float)(end - beg), 1.0f);
    float v = acc / d + hw2[(size_t)n * 64 + 48 + c] + b2[c];

    float mx = v;
#pragma unroll
    for (int off = 8; off >= 1; off >>= 1) mx = fmaxf(mx, __shfl_xor(mx, off, 16));
    float s = __expf(v - mx);
#pragma unroll
    for (int off = 8; off >= 1; off >>= 1) s += __shfl_xor(s, off, 16);
    out[gid] = v - mx - __logf(s);
}

// ---------------------------------------------------------------------------
extern "C" void kernel_launch(void* const* d_in, const int* in_sizes, int n_in,
                              void* d_out, int out_size, void* d_ws, size_t ws_size,
                              hipStream_t stream) {
    const float* x   = (const float*)d_in[0];
    const int*   ei  = (const int*)d_in[1];
    const float* ea  = (const float*)d_in[2];
    const float* g1  = (const float*)d_in[3];
    const float* mu1 = (const float*)d_in[4];
    const float* sg1 = (const float*)d_in[5];
    const float* r1  = (const float*)d_in[6];
    const float* b1  = (const float*)d_in[7];
    const float* g2  = (const float*)d_in[8];
    const float* mu2 = (const float*)d_in[9];
    const float* sg2 = (const float*)d_in[10];
    const float* r2  = (const float*)d_in[11];
    const float* b2  = (const float*)d_in[12];

    const int N = in_sizes[0] / 128;   // 50000
    const int E = in_sizes[2] / 2;     // 800000
    const int NB = (N + 255) / 256;    // scan blocks (<=256)

    // Workspace layout
    float* ws   = (float*)d_ws;
    float*  hw1 = ws;                          // N*256 floats (51.2MB); hw2 aliases front
    float*  h2  = hw1 + (size_t)N * 256;       // N*64
    float4* rec = (float4*)(h2 + (size_t)N * 64);        // E float4 (16B aligned)
    float2* eap = (float2*)((float*)rec + (size_t)E * 4); // E float2
    int*    deg    = (int*)((float*)eap + (size_t)E * 2); // N
    int*    rowptr = deg + N;                   // N+1
    int*    cursor = rowptr + N + 1;            // N
    int*    bsum   = cursor + N;                // 256
    int*    flag   = bsum + 256;                // 1
    float*  hw2 = hw1;                          // alias: hw1 dead after agg1

    hipMemsetAsync(deg, 0, sizeof(int) * N, stream);

    detect_kernel<<<1, 256, 0, stream>>>(ei, flag);
    hist_kernel<<<(E + 255) / 256, 256, 0, stream>>>(ei, flag, deg, E);
    scan_part<<<NB, 256, 0, stream>>>(deg, bsum, N);
    scan_base<<<1, 256, 0, stream>>>(bsum, NB, rowptr + N, E);
    scan_final<<<NB, 256, 0, stream>>>(deg, bsum, rowptr, cursor, N);
    scatter_kernel<<<(E + 255) / 256, 256, 0, stream>>>(
        ei, flag, (const float2*)ea, mu1, sg1, cursor, rec, eap, E);

    // Layer 1 GEMM: x [N,128] @ [g1|root1] [128,256] -> hw1
    gemm_cat<128, 64, 128, 192, 64>
        <<<dim3((N + 63) / 64, 2), 256, 0, stream>>>(x, g1, r1, hw1, N);

    agg1_kernel<<<(N * 64 + 255) / 256, 256, 0, stream>>>(rec, rowptr, hw1, b1, h2, N);

    // Layer 2 GEMM: h2 [N,64] @ [g2|root2] [64,64] -> hw2 (aliases hw1)
    gemm_cat<64, 128, 64, 48, 16>
        <<<dim3((N + 127) / 128, 1), 256, 0, stream>>>(h2, g2, r2, hw2, N);

    agg2_kernel<<<(N * 16 + 255) / 256, 256, 0, stream>>>(
        (const float*)rec, eap, rowptr, hw2, mu2, sg2, b2, (float*)d_out, N);
}

// Round 3
// 233.476 us; speedup vs baseline: 1.5186x; 1.2891x over previous
//
#include <hip/hip_runtime.h>
#include <hip/hip_fp16.h>

#define EPS 1e-15f

// ---------------------------------------------------------------------------
// Helpers
// ---------------------------------------------------------------------------
__device__ __forceinline__ int load_idx(const int* __restrict__ ei, int is64, int pos) {
    return is64 ? ei[(size_t)2 * pos] : ei[pos];
}

// Detect whether edge_index arrived as int64 (odd int32 words all zero) or int32.
__global__ void detect_kernel(const int* __restrict__ ei, int* __restrict__ flag) {
    __shared__ int any_odd;
    if (threadIdx.x == 0) any_odd = 0;
    __syncthreads();
    if (ei[2 * threadIdx.x + 1] != 0) atomicOr(&any_odd, 1);
    __syncthreads();
    if (threadIdx.x == 0) *flag = any_odd ? 0 : 1;
}

__global__ void hist_kernel(const int* __restrict__ ei, const int* __restrict__ flag,
                            int* __restrict__ deg, int E) {
    int e = blockIdx.x * 256 + threadIdx.x;
    if (e >= E) return;
    int dst = load_idx(ei, *flag, E + e);
    atomicAdd(&deg[dst], 1);
}

// ---- block-tiled exclusive scan over deg[N] ----
__global__ void scan_part(const int* __restrict__ deg, int* __restrict__ bsum, int N) {
    __shared__ int s[256];
    int i = blockIdx.x * 256 + threadIdx.x;
    s[threadIdx.x] = (i < N) ? deg[i] : 0;
    __syncthreads();
    for (int o = 128; o > 0; o >>= 1) {
        if (threadIdx.x < o) s[threadIdx.x] += s[threadIdx.x + o];
        __syncthreads();
    }
    if (threadIdx.x == 0) bsum[blockIdx.x] = s[0];
}

__global__ void scan_base(int* __restrict__ bsum, int NB, int* __restrict__ rowptrN, int E) {
    __shared__ int s[256];
    int v = (threadIdx.x < NB) ? bsum[threadIdx.x] : 0;
    s[threadIdx.x] = v;
    __syncthreads();
    for (int o = 1; o < 256; o <<= 1) {
        int t = (threadIdx.x >= o) ? s[threadIdx.x - o] : 0;
        __syncthreads();
        s[threadIdx.x] += t;
        __syncthreads();
    }
    if (threadIdx.x < NB) bsum[threadIdx.x] = s[threadIdx.x] - v;  // exclusive
    if (threadIdx.x == 0) *rowptrN = E;
}

__global__ void scan_final(const int* __restrict__ deg, const int* __restrict__ bsum,
                           int* __restrict__ rowptr, int* __restrict__ cursor, int N) {
    __shared__ int s[256];
    int i = blockIdx.x * 256 + threadIdx.x;
    int v = (i < N) ? deg[i] : 0;
    s[threadIdx.x] = v;
    __syncthreads();
    for (int o = 1; o < 256; o <<= 1) {
        int t = (threadIdx.x >= o) ? s[threadIdx.x - o] : 0;
        __syncthreads();
        s[threadIdx.x] += t;
        __syncthreads();
    }
    int excl = s[threadIdx.x] - v + bsum[blockIdx.x];
    if (i < N) { rowptr[i] = excl; cursor[i] = excl; }
}

// Scatter edges into dst-ordered records:
//   rec1 = {src_bits, g1_0, g1_1, g1_2}   (for agg1)
//   rec2 = {g2_0, g2_1, g2_2, src_bits}   (for agg2)
__global__ __launch_bounds__(256) void scatter_kernel(
    const int* __restrict__ ei, const int* __restrict__ flag,
    const float2* __restrict__ ea,
    const float* __restrict__ mu1, const float* __restrict__ sg1,
    const float* __restrict__ mu2, const float* __restrict__ sg2,
    int* __restrict__ cursor,
    float4* __restrict__ rec1, float4* __restrict__ rec2, int E) {
    int e = blockIdx.x * 256 + threadIdx.x;
    if (e >= E) return;
    int is64 = *flag;
    int src = load_idx(ei, is64, e);
    int dst = load_idx(ei, is64, E + e);
    float2 a = ea[e];
    float g1v[3], g2v[3];
#pragma unroll
    for (int k = 0; k < 3; ++k) {
        float d0 = a.x - mu1[2 * k], d1 = a.y - mu1[2 * k + 1];
        float s0 = sg1[2 * k], s1 = sg1[2 * k + 1];
        g1v[k] = __expf(-0.5f * (d0 * d0 / (EPS + s0 * s0) + d1 * d1 / (EPS + s1 * s1)));
        d0 = a.x - mu2[2 * k]; d1 = a.y - mu2[2 * k + 1];
        s0 = sg2[2 * k]; s1 = sg2[2 * k + 1];
        g2v[k] = __expf(-0.5f * (d0 * d0 / (EPS + s0 * s0) + d1 * d1 / (EPS + s1 * s1)));
    }
    int pos = atomicAdd(&cursor[dst], 1);
    rec1[pos] = make_float4(__int_as_float(src), g1v[0], g1v[1], g1v[2]);
    rec2[pos] = make_float4(g2v[0], g2v[1], g2v[2], __int_as_float(src));
}

// ---------------------------------------------------------------------------
// GEMM: Cout[n, c] = sum_k A[n,k] * W(k,c), W = [W1 | W2] concat on columns.
// Output written as fp16 (consumed only as gather tables).
// ---------------------------------------------------------------------------
template<int K, int TN, int TC, int C1, int C2>
__global__ __launch_bounds__(256) void gemm_cat(
    const float* __restrict__ A, const float* __restrict__ W1,
    const float* __restrict__ W2, __half* __restrict__ Cout, int nrows) {
    constexpr int NT = TN / 8;
    constexpr int CT = TC / 4;
    static_assert(NT * CT == 256, "bad tile");
    constexpr int COLS = C1 + C2;
    __shared__ float xs[TN][K + 4];

    int row0 = blockIdx.x * TN;
    int col0 = blockIdx.y * TC;

    constexpr int NV = TN * (K / 4);
    for (int id = threadIdx.x; id < NV; id += 256) {
        int r  = id / (K / 4);
        int k4 = id % (K / 4);
        int gr = row0 + r;
        float4 v = make_float4(0.f, 0.f, 0.f, 0.f);
        if (gr < nrows) v = reinterpret_cast<const float4*>(A + (size_t)gr * K)[k4];
        *reinterpret_cast<float4*>(&xs[r][4 * k4]) = v;
    }
    __syncthreads();

    int ct = threadIdx.x % CT;
    int nt = threadIdx.x / CT;
    int c0 = col0 + ct * 4;

    const float* wp;
    int wstride;
    if (c0 < C1) { wp = W1 + c0;        wstride = C1; }
    else         { wp = W2 + (c0 - C1); wstride = C2; }

    float acc[8][4] = {};
#pragma unroll 4
    for (int k = 0; k < K; ++k) {
        float4 w = *reinterpret_cast<const float4*>(wp + (size_t)k * wstride);
        float xr[8];
#pragma unroll
        for (int i = 0; i < 8; ++i) xr[i] = xs[nt * 8 + i][k];
#pragma unroll
        for (int i = 0; i < 8; ++i) {
            acc[i][0] += xr[i] * w.x;
            acc[i][1] += xr[i] * w.y;
            acc[i][2] += xr[i] * w.z;
            acc[i][3] += xr[i] * w.w;
        }
    }

#pragma unroll
    for (int i = 0; i < 8; ++i) {
        int gr = row0 + nt * 8 + i;
        if (gr < nrows) {
            __half2* p = reinterpret_cast<__half2*>(Cout + (size_t)gr * COLS + c0);
            p[0] = __floats2half2_rn(acc[i][0], acc[i][1]);
            p[1] = __floats2half2_rn(acc[i][2], acc[i][3]);
        }
    }
}

// ---------------------------------------------------------------------------
// agg1: 32 lanes per node, each lane owns m = {2l, 2l+1} via half2.
// hw1h [N,256] halves: cols k*64+m (k<3), cols 192..255 = root part.
// Fused mean + root + bias + ELU -> h2 (fp32 [N,64]).
// ---------------------------------------------------------------------------
__global__ __launch_bounds__(256) void agg1_kernel(
    const float4* __restrict__ rec1, const int* __restrict__ rowptr,
    const __half* __restrict__ hw1h, const float* __restrict__ b1,
    float* __restrict__ h2, int N) {
    int node = (blockIdx.x * 256 + threadIdx.x) >> 5;
    int l = threadIdx.x & 31;
    if (node >= N) return;
    int beg = rowptr[node], end = rowptr[node + 1];
    float ax0 = 0.f, ay0 = 0.f, ax1 = 0.f, ay1 = 0.f;
    int j = beg;
    for (; j + 1 < end; j += 2) {
        float4 r0 = rec1[j], r1 = rec1[j + 1];
        const __half2* p0 = reinterpret_cast<const __half2*>(
            hw1h + (size_t)__float_as_int(r0.x) * 256);
        const __half2* p1 = reinterpret_cast<const __half2*>(
            hw1h + (size_t)__float_as_int(r1.x) * 256);
        float2 f00 = __half22float2(p0[l]);
        float2 f01 = __half22float2(p0[32 + l]);
        float2 f02 = __half22float2(p0[64 + l]);
        float2 f10 = __half22float2(p1[l]);
        float2 f11 = __half22float2(p1[32 + l]);
        float2 f12 = __half22float2(p1[64 + l]);
        ax0 += r0.y * f00.x + r0.z * f01.x + r0.w * f02.x;
        ay0 += r0.y * f00.y + r0.z * f01.y + r0.w * f02.y;
        ax1 += r1.y * f10.x + r1.z * f11.x + r1.w * f12.x;
        ay1 += r1.y * f10.y + r1.z * f11.y + r1.w * f12.y;
    }
    if (j < end) {
        float4 r0 = rec1[j];
        const __half2* p0 = reinterpret_cast<const __half2*>(
            hw1h + (size_t)__float_as_int(r0.x) * 256);
        float2 f00 = __half22float2(p0[l]);
        float2 f01 = __half22float2(p0[32 + l]);
        float2 f02 = __half22float2(p0[64 + l]);
        ax0 += r0.y * f00.x + r0.z * f01.x + r0.w * f02.x;
        ay0 += r0.y * f00.y + r0.z * f01.y + r0.w * f02.y;
    }
    float d = fmaxf((float)(end - beg), 1.0f);
    float2 root = __half22float2(
        reinterpret_cast<const __half2*>(hw1h + (size_t)node * 256 + 192)[l]);
    float2 bb = reinterpret_cast<const float2*>(b1)[l];
    float v0 = (ax0 + ax1) / d + root.x + bb.x;
    float v1 = (ay0 + ay1) / d + root.y + bb.y;
    float2 o;
    o.x = v0 > 0.f ? v0 : expm1f(v0);
    o.y = v1 > 0.f ? v1 : expm1f(v1);
    reinterpret_cast<float2*>(h2 + (size_t)node * 64)[l] = o;
}

// ---------------------------------------------------------------------------
// agg2: 8 lanes per node, each lane owns c = {2l, 2l+1} via half2.
// hw2h [N,64] halves: cols k*16+c (k<3), cols 48..63 = root part.
// Fused mean + root + bias + log_softmax -> out [N,16].
// ---------------------------------------------------------------------------
__global__ __launch_bounds__(256) void agg2_kernel(
    const float4* __restrict__ rec2, const int* __restrict__ rowptr,
    const __half* __restrict__ hw2h, const float* __restrict__ b2,
    float* __restrict__ out, int N) {
    int node = (blockIdx.x * 256 + threadIdx.x) >> 3;
    int l = threadIdx.x & 7;
    if (node >= N) return;
    int beg = rowptr[node], end = rowptr[node + 1];
    float ax = 0.f, ay = 0.f;
    for (int j = beg; j < end; ++j) {
        float4 r = rec2[j];
        const __half2* p = reinterpret_cast<const __half2*>(
            hw2h + (size_t)__float_as_int(r.w) * 64);
        float2 f0 = __half22float2(p[l]);
        float2 f1 = __half22float2(p[8 + l]);
        float2 f2 = __half22float2(p[16 + l]);
        ax += r.x * f0.x + r.y * f1.x + r.z * f2.x;
        ay += r.x * f0.y + r.y * f1.y + r.z * f2.y;
    }
    float d = fmaxf((float)(end - beg), 1.0f);
    float2 root = __half22float2(
        reinterpret_cast<const __half2*>(hw2h + (size_t)node * 64 + 48)[l]);
    float2 bb = reinterpret_cast<const float2*>(b2)[l];
    float v0 = ax / d + root.x + bb.x;
    float v1 = ay / d + root.y + bb.y;

    float mx = fmaxf(v0, v1);
#pragma unroll
    for (int off = 4; off >= 1; off >>= 1) mx = fmaxf(mx, __shfl_xor(mx, off, 8));
    float s = __expf(v0 - mx) + __expf(v1 - mx);
#pragma unroll
    for (int off = 4; off >= 1; off >>= 1) s += __shfl_xor(s, off, 8);
    float ls = __logf(s);
    float2 o = make_float2(v0 - mx - ls, v1 - mx - ls);
    reinterpret_cast<float2*>(out + (size_t)node * 16)[l] = o;
}

// ---------------------------------------------------------------------------
extern "C" void kernel_launch(void* const* d_in, const int* in_sizes, int n_in,
                              void* d_out, int out_size, void* d_ws, size_t ws_size,
                              hipStream_t stream) {
    const float* x   = (const float*)d_in[0];
    const int*   ei  = (const int*)d_in[1];
    const float* ea  = (const float*)d_in[2];
    const float* g1  = (const float*)d_in[3];
    const float* mu1 = (const float*)d_in[4];
    const float* sg1 = (const float*)d_in[5];
    const float* r1  = (const float*)d_in[6];
    const float* b1  = (const float*)d_in[7];
    const float* g2  = (const float*)d_in[8];
    const float* mu2 = (const float*)d_in[9];
    const float* sg2 = (const float*)d_in[10];
    const float* r2  = (const float*)d_in[11];
    const float* b2  = (const float*)d_in[12];

    const int N = in_sizes[0] / 128;   // 50000
    const int E = in_sizes[2] / 2;     // 800000
    const int NB = (N + 255) / 256;

    // Workspace layout
    __half* hw1h = (__half*)d_ws;                         // N*256 halves (25.6MB)
    float*  h2   = (float*)(hw1h + (size_t)N * 256);      // N*64 fp32
    __half* hw2h = (__half*)(h2 + (size_t)N * 64);        // N*64 halves
    float4* rec1 = (float4*)(hw2h + (size_t)N * 64);      // E float4
    float4* rec2 = rec1 + E;                              // E float4
    int*    deg    = (int*)(rec2 + E);                    // N
    int*    rowptr = deg + N;                             // N+1
    int*    cursor = rowptr + N + 1;                      // N
    int*    bsum   = cursor + N;                          // 256
    int*    flag   = bsum + 256;                          // 1

    hipMemsetAsync(deg, 0, sizeof(int) * N, stream);

    detect_kernel<<<1, 256, 0, stream>>>(ei, flag);
    hist_kernel<<<(E + 255) / 256, 256, 0, stream>>>(ei, flag, deg, E);
    scan_part<<<NB, 256, 0, stream>>>(deg, bsum, N);
    scan_base<<<1, 256, 0, stream>>>(bsum, NB, rowptr + N, E);
    scan_final<<<NB, 256, 0, stream>>>(deg, bsum, rowptr, cursor, N);
    scatter_kernel<<<(E + 255) / 256, 256, 0, stream>>>(
        ei, flag, (const float2*)ea, mu1, sg1, mu2, sg2, cursor, rec1, rec2, E);

    // Layer 1 GEMM: x [N,128] @ [g1|root1] [128,256] -> hw1h (fp16)
    gemm_cat<128, 64, 128, 192, 64>
        <<<dim3((N + 63) / 64, 2), 256, 0, stream>>>(x, g1, r1, hw1h, N);

    agg1_kernel<<<((size_t)N * 32 + 255) / 256, 256, 0, stream>>>(
        rec1, rowptr, hw1h, b1, h2, N);

    // Layer 2 GEMM: h2 [N,64] @ [g2|root2] [64,64] -> hw2h (fp16)
    gemm_cat<64, 128, 64, 48, 16>
        <<<dim3((N + 127) / 128, 1), 256, 0, stream>>>(h2, g2, r2, hw2h, N);

    agg2_kernel<<<((size_t)N * 8 + 255) / 256, 256, 0, stream>>>(
        rec2, rowptr, hw2h, b2, (float*)d_out, N);
}

// Round 4
// 224.459 us; speedup vs baseline: 1.5796x; 1.0402x over previous
//
#include <hip/hip_runtime.h>
#include <hip/hip_fp16.h>

#define EPS 1e-15f

typedef _Float16 v8h __attribute__((ext_vector_type(8)));
typedef float v4f __attribute__((ext_vector_type(4)));

// ---------------------------------------------------------------------------
// Helpers
// ---------------------------------------------------------------------------
__device__ __forceinline__ int load_idx(const int* __restrict__ ei, int is64, int pos) {
    return is64 ? ei[(size_t)2 * pos] : ei[pos];
}

__device__ __forceinline__ int h2_as_int(__half2 h) {
    int w; __builtin_memcpy(&w, &h, 4); return w;
}
__device__ __forceinline__ __half2 int_as_h2(int w) {
    __half2 h; __builtin_memcpy(&h, &w, 4); return h;
}

// Detect whether edge_index arrived as int64 (odd int32 words all zero) or int32.
__global__ void detect_kernel(const int* __restrict__ ei, int* __restrict__ flag) {
    __shared__ int any_odd;
    if (threadIdx.x == 0) any_odd = 0;
    __syncthreads();
    if (ei[2 * threadIdx.x + 1] != 0) atomicOr(&any_odd, 1);
    __syncthreads();
    if (threadIdx.x == 0) *flag = any_odd ? 0 : 1;
}

__global__ void hist_kernel(const int* __restrict__ ei, const int* __restrict__ flag,
                            int* __restrict__ deg, int E) {
    int e = blockIdx.x * 256 + threadIdx.x;
    if (e >= E) return;
    int dst = load_idx(ei, *flag, E + e);
    atomicAdd(&deg[dst], 1);
}

// ---- block-tiled exclusive scan over deg[N] ----
__global__ void scan_part(const int* __restrict__ deg, int* __restrict__ bsum, int N) {
    __shared__ int s[256];
    int i = blockIdx.x * 256 + threadIdx.x;
    s[threadIdx.x] = (i < N) ? deg[i] : 0;
    __syncthreads();
    for (int o = 128; o > 0; o >>= 1) {
        if (threadIdx.x < o) s[threadIdx.x] += s[threadIdx.x + o];
        __syncthreads();
    }
    if (threadIdx.x == 0) bsum[blockIdx.x] = s[0];
}

__global__ void scan_base(int* __restrict__ bsum, int NB, int* __restrict__ rowptrN, int E) {
    __shared__ int s[256];
    int v = (threadIdx.x < NB) ? bsum[threadIdx.x] : 0;
    s[threadIdx.x] = v;
    __syncthreads();
    for (int o = 1; o < 256; o <<= 1) {
        int t = (threadIdx.x >= o) ? s[threadIdx.x - o] : 0;
        __syncthreads();
        s[threadIdx.x] += t;
        __syncthreads();
    }
    if (threadIdx.x < NB) bsum[threadIdx.x] = s[threadIdx.x] - v;  // exclusive
    if (threadIdx.x == 0) *rowptrN = E;
}

__global__ void scan_final(const int* __restrict__ deg, const int* __restrict__ bsum,
                           int* __restrict__ rowptr, int* __restrict__ cursor, int N) {
    __shared__ int s[256];
    int i = blockIdx.x * 256 + threadIdx.x;
    int v = (i < N) ? deg[i] : 0;
    s[threadIdx.x] = v;
    __syncthreads();
    for (int o = 1; o < 256; o <<= 1) {
        int t = (threadIdx.x >= o) ? s[threadIdx.x - o] : 0;
        __syncthreads();
        s[threadIdx.x] += t;
        __syncthreads();
    }
    int excl = s[threadIdx.x] - v + bsum[blockIdx.x];
    if (i < N) { rowptr[i] = excl; cursor[i] = excl; }
}

// Scatter edges into dst-ordered records:
//   rec = {src:int32, h2(g1_0,g1_1), h2(g1_2,g2_0), h2(g2_1,g2_2)}  (16B)
__global__ __launch_bounds__(256) void scatter_kernel(
    const int* __restrict__ ei, const int* __restrict__ flag,
    const float2* __restrict__ ea,
    const float* __restrict__ mu1, const float* __restrict__ sg1,
    const float* __restrict__ mu2, const float* __restrict__ sg2,
    int* __restrict__ cursor, int4* __restrict__ rec, int E) {
    int e = blockIdx.x * 256 + threadIdx.x;
    if (e >= E) return;
    int is64 = *flag;
    int src = load_idx(ei, is64, e);
    int dst = load_idx(ei, is64, E + e);
    float2 a = ea[e];
    float g1v[3], g2v[3];
#pragma unroll
    for (int k = 0; k < 3; ++k) {
        float d0 = a.x - mu1[2 * k], d1 = a.y - mu1[2 * k + 1];
        float s0 = sg1[2 * k], s1 = sg1[2 * k + 1];
        g1v[k] = __expf(-0.5f * (d0 * d0 / (EPS + s0 * s0) + d1 * d1 / (EPS + s1 * s1)));
        d0 = a.x - mu2[2 * k]; d1 = a.y - mu2[2 * k + 1];
        s0 = sg2[2 * k]; s1 = sg2[2 * k + 1];
        g2v[k] = __expf(-0.5f * (d0 * d0 / (EPS + s0 * s0) + d1 * d1 / (EPS + s1 * s1)));
    }
    int pos = atomicAdd(&cursor[dst], 1);
    int4 r;
    r.x = src;
    r.y = h2_as_int(__floats2half2_rn(g1v[0], g1v[1]));
    r.z = h2_as_int(__floats2half2_rn(g1v[2], g2v[0]));
    r.w = h2_as_int(__floats2half2_rn(g2v[1], g2v[2]));
    rec[pos] = r;
}

// ---------------------------------------------------------------------------
// Bprep: fragment-ordered fp16 copy of W = [g1 | r1]  (128 x 256).
// frag fi = cb*4 + ks (cb: 16-col block 0..15, ks: 32-K step 0..3):
//   Bprep[fi*512 + lane*8 + i] = W[ks*32 + (lane>>4)*8 + i][cb*16 + (lane&15)]
// ---------------------------------------------------------------------------
__global__ void bprep_kernel(const float* __restrict__ g1, const float* __restrict__ r1,
                             __half* __restrict__ Bprep) {
    int gid = blockIdx.x * 256 + threadIdx.x;   // 32768 total
    if (gid >= 32768) return;
    int fi = gid >> 9;
    int lane = (gid >> 3) & 63;
    int i = gid & 7;
    int ks = fi & 3, cb = fi >> 2;
    int k = ks * 32 + (lane >> 4) * 8 + i;
    int c = cb * 16 + (lane & 15);
    float v = (c < 192) ? g1[k * 192 + c] : r1[k * 64 + (c - 192)];
    Bprep[gid] = __float2half(v);
}

// ---------------------------------------------------------------------------
// Layer-1 GEMM via MFMA f16: x [M,128] fp32 -> hw1h [M,256] fp16.
// BM=128, BN=128 (blockIdx.y in {0,1}), full K=128 staged in swizzled LDS.
// 4 waves: (wr, wc) in 2x2, each wave 64 rows x 64 cols = 4x4 16x16 frags.
// ---------------------------------------------------------------------------
__global__ __launch_bounds__(256) void gemm1_mfma(
    const float* __restrict__ A, const __half* __restrict__ Bprep,
    __half* __restrict__ Cout, int M) {
    __shared__ char a_lds[128 * 256];   // 128 rows x 128 fp16 (256B/row), XOR-swizzled
    int row0 = blockIdx.x * 128;
    int tid = threadIdx.x;

    // Stage A: thread t handles row t>>1, k-half (t&1)*64 (64 fp32 -> 64 fp16)
    {
        int r = tid >> 1;
        int kh = (tid & 1) * 64;
        int gr = row0 + r;
        bool valid = gr < M;
        const float4* src = reinterpret_cast<const float4*>(A + (size_t)gr * 128 + kh);
#pragma unroll
        for (int i = 0; i < 8; ++i) {   // 8 chunks of 8 fp32 -> 8 fp16 (16B)
            float4 f0 = valid ? src[2 * i]     : make_float4(0.f, 0.f, 0.f, 0.f);
            float4 f1 = valid ? src[2 * i + 1] : make_float4(0.f, 0.f, 0.f, 0.f);
            int4 v;
            v.x = h2_as_int(__floats2half2_rn(f0.x, f0.y));
            v.y = h2_as_int(__floats2half2_rn(f0.z, f0.w));
            v.z = h2_as_int(__floats2half2_rn(f1.x, f1.y));
            v.w = h2_as_int(__floats2half2_rn(f1.z, f1.w));
            int byte = r * 256 + kh * 2 + i * 16;
            byte ^= (r & 7) << 4;       // T2 swizzle
            *reinterpret_cast<int4*>(&a_lds[byte]) = v;
        }
    }

    int wid = tid >> 6, lane = tid & 63;
    int wr = wid & 1, wc = wid >> 1;

    // Preload all 16 loop-invariant B fragments (coalesced, L2-resident)
    v8h bf[4][4];   // [cf][ks]
#pragma unroll
    for (int cf = 0; cf < 4; ++cf)
#pragma unroll
        for (int ks = 0; ks < 4; ++ks) {
            int cb = blockIdx.y * 8 + wc * 4 + cf;
            int fi = cb * 4 + ks;
            bf[cf][ks] = *reinterpret_cast<const v8h*>(Bprep + (size_t)fi * 512 + lane * 8);
        }

    __syncthreads();

    v4f acc[4][4] = {};   // [rf][cf]
#pragma unroll
    for (int ks = 0; ks < 4; ++ks) {
        v8h af[4];
#pragma unroll
        for (int rf = 0; rf < 4; ++rf) {
            int r = wr * 64 + rf * 16 + (lane & 15);
            int byte = r * 256 + ks * 64 + (lane >> 4) * 16;
            byte ^= (r & 7) << 4;
            af[rf] = *reinterpret_cast<const v8h*>(&a_lds[byte]);
        }
#pragma unroll
        for (int rf = 0; rf < 4; ++rf)
#pragma unroll
            for (int cf = 0; cf < 4; ++cf)
                acc[rf][cf] = __builtin_amdgcn_mfma_f32_16x16x32_f16(
                    af[rf], bf[cf][ks], acc[rf][cf], 0, 0, 0);
    }

    // Write C: D[m = (lane>>4)*4 + i][n = lane&15] per frag
#pragma unroll
    for (int rf = 0; rf < 4; ++rf)
#pragma unroll
        for (int cf = 0; cf < 4; ++cf)
#pragma unroll
            for (int i = 0; i < 4; ++i) {
                int gr = row0 + wr * 64 + rf * 16 + (lane >> 4) * 4 + i;
                int gc = blockIdx.y * 128 + wc * 64 + cf * 16 + (lane & 15);
                if (gr < M) Cout[(size_t)gr * 256 + gc] = __float2half(acc[rf][cf][i]);
            }
}

// ---------------------------------------------------------------------------
// Vector GEMM (layer 2): Cout[n,c] = A[n,:] @ [W1|W2], fp16 out.
// ---------------------------------------------------------------------------
template<int K, int TN, int TC, int C1, int C2>
__global__ __launch_bounds__(256) void gemm_cat(
    const float* __restrict__ A, const float* __restrict__ W1,
    const float* __restrict__ W2, __half* __restrict__ Cout, int nrows) {
    constexpr int NT = TN / 8;
    constexpr int CT = TC / 4;
    static_assert(NT * CT == 256, "bad tile");
    constexpr int COLS = C1 + C2;
    __shared__ float xs[TN][K + 4];

    int row0 = blockIdx.x * TN;
    int col0 = blockIdx.y * TC;

    constexpr int NV = TN * (K / 4);
    for (int id = threadIdx.x; id < NV; id += 256) {
        int r  = id / (K / 4);
        int k4 = id % (K / 4);
        int gr = row0 + r;
        float4 v = make_float4(0.f, 0.f, 0.f, 0.f);
        if (gr < nrows) v = reinterpret_cast<const float4*>(A + (size_t)gr * K)[k4];
        *reinterpret_cast<float4*>(&xs[r][4 * k4]) = v;
    }
    __syncthreads();

    int ct = threadIdx.x % CT;
    int nt = threadIdx.x / CT;
    int c0 = col0 + ct * 4;

    const float* wp;
    int wstride;
    if (c0 < C1) { wp = W1 + c0;        wstride = C1; }
    else         { wp = W2 + (c0 - C1); wstride = C2; }

    float acc[8][4] = {};
#pragma unroll 4
    for (int k = 0; k < K; ++k) {
        float4 w = *reinterpret_cast<const float4*>(wp + (size_t)k * wstride);
        float xr[8];
#pragma unroll
        for (int i = 0; i < 8; ++i) xr[i] = xs[nt * 8 + i][k];
#pragma unroll
        for (int i = 0; i < 8; ++i) {
            acc[i][0] += xr[i] * w.x;
            acc[i][1] += xr[i] * w.y;
            acc[i][2] += xr[i] * w.z;
            acc[i][3] += xr[i] * w.w;
        }
    }

#pragma unroll
    for (int i = 0; i < 8; ++i) {
        int gr = row0 + nt * 8 + i;
        if (gr < nrows) {
            __half2* p = reinterpret_cast<__half2*>(Cout + (size_t)gr * COLS + c0);
            p[0] = __floats2half2_rn(acc[i][0], acc[i][1]);
            p[1] = __floats2half2_rn(acc[i][2], acc[i][3]);
        }
    }
}

// ---------------------------------------------------------------------------
// agg1: 32 lanes per node, lane owns m = {2l, 2l+1} via half2.
// hw1h [N,256]: cols k*64+m (k<3), cols 192..255 = root part.
// Fused mean + root + bias + ELU -> h2 (fp32 [N,64]).
// ---------------------------------------------------------------------------
__global__ __launch_bounds__(256) void agg1_kernel(
    const int4* __restrict__ rec, const int* __restrict__ rowptr,
    const __half* __restrict__ hw1h, const float* __restrict__ b1,
    float* __restrict__ h2, int N) {
    int node = (blockIdx.x * 256 + threadIdx.x) >> 5;
    int l = threadIdx.x & 31;
    if (node >= N) return;
    int beg = rowptr[node], end = rowptr[node + 1];
    float ax0 = 0.f, ay0 = 0.f, ax1 = 0.f, ay1 = 0.f;
    int j = beg;
    for (; j + 1 < end; j += 2) {
        int4 r0 = rec[j], r1 = rec[j + 1];
        __half2 ha0 = int_as_h2(r0.y), hb0 = int_as_h2(r0.z);
        __half2 ha1 = int_as_h2(r1.y), hb1 = int_as_h2(r1.z);
        float g00 = __low2float(ha0), g01 = __high2float(ha0), g02 = __low2float(hb0);
        float g10 = __low2float(ha1), g11 = __high2float(ha1), g12 = __low2float(hb1);
        const __half2* p0 = reinterpret_cast<const __half2*>(hw1h + (size_t)r0.x * 256);
        const __half2* p1 = reinterpret_cast<const __half2*>(hw1h + (size_t)r1.x * 256);
        float2 f00 = __half22float2(p0[l]);
        float2 f01 = __half22float2(p0[32 + l]);
        float2 f02 = __half22float2(p0[64 + l]);
        float2 f10 = __half22float2(p1[l]);
        float2 f11 = __half22float2(p1[32 + l]);
        float2 f12 = __half22float2(p1[64 + l]);
        ax0 += g00 * f00.x + g01 * f01.x + g02 * f02.x;
        ay0 += g00 * f00.y + g01 * f01.y + g02 * f02.y;
        ax1 += g10 * f10.x + g11 * f11.x + g12 * f12.x;
        ay1 += g10 * f10.y + g11 * f11.y + g12 * f12.y;
    }
    if (j < end) {
        int4 r0 = rec[j];
        __half2 ha0 = int_as_h2(r0.y), hb0 = int_as_h2(r0.z);
        float g00 = __low2float(ha0), g01 = __high2float(ha0), g02 = __low2float(hb0);
        const __half2* p0 = reinterpret_cast<const __half2*>(hw1h + (size_t)r0.x * 256);
        float2 f00 = __half22float2(p0[l]);
        float2 f01 = __half22float2(p0[32 + l]);
        float2 f02 = __half22float2(p0[64 + l]);
        ax0 += g00 * f00.x + g01 * f01.x + g02 * f02.x;
        ay0 += g00 * f00.y + g01 * f01.y + g02 * f02.y;
    }
    float d = fmaxf((float)(end - beg), 1.0f);
    float2 root = __half22float2(
        reinterpret_cast<const __half2*>(hw1h + (size_t)node * 256 + 192)[l]);
    float2 bb = reinterpret_cast<const float2*>(b1)[l];
    float v0 = (ax0 + ax1) / d + root.x + bb.x;
    float v1 = (ay0 + ay1) / d + root.y + bb.y;
    float2 o;
    o.x = v0 > 0.f ? v0 : expm1f(v0);
    o.y = v1 > 0.f ? v1 : expm1f(v1);
    reinterpret_cast<float2*>(h2 + (size_t)node * 64)[l] = o;
}

// ---------------------------------------------------------------------------
// agg2: 8 lanes per node, lane owns c = {2l, 2l+1} via half2.
// hw2h [N,64]: cols k*16+c (k<3), cols 48..63 = root part.
// Fused mean + root + bias + log_softmax -> out [N,16].
// ---------------------------------------------------------------------------
__global__ __launch_bounds__(256) void agg2_kernel(
    const int4* __restrict__ rec, const int* __restrict__ rowptr,
    const __half* __restrict__ hw2h, const float* __restrict__ b2,
    float* __restrict__ out, int N) {
    int node = (blockIdx.x * 256 + threadIdx.x) >> 3;
    int l = threadIdx.x & 7;
    if (node >= N) return;
    int beg = rowptr[node], end = rowptr[node + 1];
    float ax = 0.f, ay = 0.f;
    for (int j = beg; j < end; ++j) {
        int4 r = rec[j];
        __half2 hb = int_as_h2(r.z), hc = int_as_h2(r.w);
        float g0 = __high2float(hb), g1 = __low2float(hc), g2 = __high2float(hc);
        const __half2* p = reinterpret_cast<const __half2*>(hw2h + (size_t)r.x * 64);
        float2 f0 = __half22float2(p[l]);
        float2 f1 = __half22float2(p[8 + l]);
        float2 f2 = __half22float2(p[16 + l]);
        ax += g0 * f0.x + g1 * f1.x + g2 * f2.x;
        ay += g0 * f0.y + g1 * f1.y + g2 * f2.y;
    }
    float d = fmaxf((float)(end - beg), 1.0f);
    float2 root = __half22float2(
        reinterpret_cast<const __half2*>(hw2h + (size_t)node * 64 + 48)[l]);
    float2 bb = reinterpret_cast<const float2*>(b2)[l];
    float v0 = ax / d + root.x + bb.x;
    float v1 = ay / d + root.y + bb.y;

    float mx = fmaxf(v0, v1);
#pragma unroll
    for (int off = 4; off >= 1; off >>= 1) mx = fmaxf(mx, __shfl_xor(mx, off, 8));
    float s = __expf(v0 - mx) + __expf(v1 - mx);
#pragma unroll
    for (int off = 4; off >= 1; off >>= 1) s += __shfl_xor(s, off, 8);
    float ls = __logf(s);
    float2 o = make_float2(v0 - mx - ls, v1 - mx - ls);
    reinterpret_cast<float2*>(out + (size_t)node * 16)[l] = o;
}

// ---------------------------------------------------------------------------
extern "C" void kernel_launch(void* const* d_in, const int* in_sizes, int n_in,
                              void* d_out, int out_size, void* d_ws, size_t ws_size,
                              hipStream_t stream) {
    const float* x   = (const float*)d_in[0];
    const int*   ei  = (const int*)d_in[1];
    const float* ea  = (const float*)d_in[2];
    const float* g1  = (const float*)d_in[3];
    const float* mu1 = (const float*)d_in[4];
    const float* sg1 = (const float*)d_in[5];
    const float* r1  = (const float*)d_in[6];
    const float* b1  = (const float*)d_in[7];
    const float* g2  = (const float*)d_in[8];
    const float* mu2 = (const float*)d_in[9];
    const float* sg2 = (const float*)d_in[10];
    const float* r2  = (const float*)d_in[11];
    const float* b2  = (const float*)d_in[12];

    const int N = in_sizes[0] / 128;   // 50000
    const int E = in_sizes[2] / 2;     // 800000
    const int NB = (N + 255) / 256;

    // Workspace layout
    __half* hw1h = (__half*)d_ws;                         // N*256 halves (25.6MB)
    float*  h2   = (float*)(hw1h + (size_t)N * 256);      // N*64 fp32
    __half* hw2h = (__half*)(h2 + (size_t)N * 64);        // N*64 halves
    int4*   rec  = (int4*)(hw2h + (size_t)N * 64);        // E int4 (12.8MB)
    __half* Bprep = (__half*)(rec + E);                   // 32768 halves
    int*    deg    = (int*)(Bprep + 32768);               // N
    int*    rowptr = deg + N;                             // N+1
    int*    cursor = rowptr + N + 1;                      // N
    int*    bsum   = cursor + N;                          // 256
    int*    flag   = bsum + 256;                          // 1

    hipMemsetAsync(deg, 0, sizeof(int) * N, stream);

    detect_kernel<<<1, 256, 0, stream>>>(ei, flag);
    hist_kernel<<<(E + 255) / 256, 256, 0, stream>>>(ei, flag, deg, E);
    scan_part<<<NB, 256, 0, stream>>>(deg, bsum, N);
    scan_base<<<1, 256, 0, stream>>>(bsum, NB, rowptr + N, E);
    scan_final<<<NB, 256, 0, stream>>>(deg, bsum, rowptr, cursor, N);
    scatter_kernel<<<(E + 255) / 256, 256, 0, stream>>>(
        ei, flag, (const float2*)ea, mu1, sg1, mu2, sg2, cursor, rec, E);

    // Layer 1 GEMM (MFMA): x [N,128] @ [g1|root1] -> hw1h fp16 [N,256]
    bprep_kernel<<<128, 256, 0, stream>>>(g1, r1, Bprep);
    gemm1_mfma<<<dim3((N + 127) / 128, 2), 256, 0, stream>>>(x, Bprep, hw1h, N);

    agg1_kernel<<<((size_t)N * 32 + 255) / 256, 256, 0, stream>>>(
        rec, rowptr, hw1h, b1, h2, N);

    // Layer 2 GEMM: h2 [N,64] @ [g2|root2] [64,64] -> hw2h (fp16)
    gemm_cat<64, 128, 64, 48, 16>
        <<<dim3((N + 127) / 128, 1), 256, 0, stream>>>(h2, g2, r2, hw2h, N);

    agg2_kernel<<<((size_t)N * 8 + 255) / 256, 256, 0, stream>>>(
        rec, rowptr, hw2h, b2, (float*)d_out, N);
}

// Round 5
// 217.961 us; speedup vs baseline: 1.6267x; 1.0298x over previous
//
#include <hip/hip_runtime.h>
#include <hip/hip_fp16.h>

#define EPS 1e-15f
#define BKT_SHIFT 7
#define BKT_SIZE 128

typedef _Float16 v8h __attribute__((ext_vector_type(8)));
typedef float v4f __attribute__((ext_vector_type(4)));

// ---------------------------------------------------------------------------
// Helpers
// ---------------------------------------------------------------------------
__device__ __forceinline__ int load_idx(const int* __restrict__ ei, int is64, int pos) {
    return is64 ? ei[(size_t)2 * pos] : ei[pos];
}

__device__ __forceinline__ int h2_as_int(__half2 h) {
    int w; __builtin_memcpy(&w, &h, 4); return w;
}
__device__ __forceinline__ __half2 int_as_h2(int w) {
    __half2 h; __builtin_memcpy(&h, &w, 4); return h;
}

// Detect whether edge_index arrived as int64 (odd int32 words all zero) or int32.
__global__ void detect_kernel(const int* __restrict__ ei, int* __restrict__ flag) {
    __shared__ int any_odd;
    if (threadIdx.x == 0) any_odd = 0;
    __syncthreads();
    if (ei[2 * threadIdx.x + 1] != 0) atomicOr(&any_odd, 1);
    __syncthreads();
    if (threadIdx.x == 0) *flag = any_odd ? 0 : 1;
}

__global__ void hist_kernel(const int* __restrict__ ei, const int* __restrict__ flag,
                            int* __restrict__ deg, int E) {
    int e = blockIdx.x * 256 + threadIdx.x;
    if (e >= E) return;
    int dst = load_idx(ei, *flag, E + e);
    atomicAdd(&deg[dst], 1);
}

// ---- block-tiled exclusive scan over deg[N] ----
__global__ void scan_part(const int* __restrict__ deg, int* __restrict__ bsum, int N) {
    __shared__ int s[256];
    int i = blockIdx.x * 256 + threadIdx.x;
    s[threadIdx.x] = (i < N) ? deg[i] : 0;
    __syncthreads();
    for (int o = 128; o > 0; o >>= 1) {
        if (threadIdx.x < o) s[threadIdx.x] += s[threadIdx.x + o];
        __syncthreads();
    }
    if (threadIdx.x == 0) bsum[blockIdx.x] = s[0];
}

__global__ void scan_base(int* __restrict__ bsum, int NB, int* __restrict__ rowptrN, int E) {
    __shared__ int s[256];
    int v = (threadIdx.x < NB) ? bsum[threadIdx.x] : 0;
    s[threadIdx.x] = v;
    __syncthreads();
    for (int o = 1; o < 256; o <<= 1) {
        int t = (threadIdx.x >= o) ? s[threadIdx.x - o] : 0;
        __syncthreads();
        s[threadIdx.x] += t;
        __syncthreads();
    }
    if (threadIdx.x < NB) bsum[threadIdx.x] = s[threadIdx.x] - v;  // exclusive
    if (threadIdx.x == 0) *rowptrN = E;
}

__global__ void scan_final(const int* __restrict__ deg, const int* __restrict__ bsum,
                           int* __restrict__ rowptr, int N) {
    __shared__ int s[256];
    int i = blockIdx.x * 256 + threadIdx.x;
    int v = (i < N) ? deg[i] : 0;
    s[threadIdx.x] = v;
    __syncthreads();
    for (int o = 1; o < 256; o <<= 1) {
        int t = (threadIdx.x >= o) ? s[threadIdx.x - o] : 0;
        __syncthreads();
        s[threadIdx.x] += t;
        __syncthreads();
    }
    int excl = s[threadIdx.x] - v + bsum[blockIdx.x];
    if (i < N) rowptr[i] = excl;
}

// bcursor[b] = rowptr[b * BKT_SIZE]
__global__ void bkt_init(const int* __restrict__ rowptr, int* __restrict__ bcursor,
                         int nbkt) {
    int b = blockIdx.x * 256 + threadIdx.x;
    if (b < nbkt) bcursor[b] = rowptr[b << BKT_SHIFT];
}

// ---------------------------------------------------------------------------
// Pass 1: block-aggregated bucket multisplit. 1024 edges/block.
// Packet {src, dst, ax, ay} written in contiguous runs per bucket.
// ---------------------------------------------------------------------------
__global__ __launch_bounds__(256) void pass1_kernel(
    const int* __restrict__ ei, const int* __restrict__ flag,
    const float2* __restrict__ ea, int* __restrict__ bcursor,
    int4* __restrict__ staging, int E, int nbkt) {
    __shared__ int lcnt[512];
    __shared__ int lbase[512];
    int t = threadIdx.x;
    for (int u = t; u < nbkt; u += 256) lcnt[u] = 0;
    __syncthreads();
    int is64 = *flag;
    int e0 = blockIdx.x * 1024;

    int src[4], dst[4], rk[4];
    float2 a[4];
#pragma unroll
    for (int i = 0; i < 4; ++i) {
        int e = e0 + i * 256 + t;
        if (e < E) {
            src[i] = load_idx(ei, is64, e);
            dst[i] = load_idx(ei, is64, E + e);
            a[i] = ea[e];
            rk[i] = atomicAdd(&lcnt[dst[i] >> BKT_SHIFT], 1);
        } else dst[i] = -1;
    }
    __syncthreads();
    for (int u = t; u < nbkt; u += 256)
        if (lcnt[u] > 0) lbase[u] = atomicAdd(&bcursor[u], lcnt[u]);
    __syncthreads();
#pragma unroll
    for (int i = 0; i < 4; ++i) {
        if (dst[i] >= 0) {
            int pos = lbase[dst[i] >> BKT_SHIFT] + rk[i];
            staging[pos] = make_int4(src[i], dst[i],
                                     __float_as_int(a[i].x), __float_as_int(a[i].y));
        }
    }
}

// ---------------------------------------------------------------------------
// Pass 2: one block per bucket. Final dst-order placement via LDS cursors,
// gaussians computed here. Random stores confined to a ~32KB region (L2-hot).
//   rec = {src:int32, h2(g1_0,g1_1), h2(g1_2,g2_0), h2(g2_1,g2_2)}
// ---------------------------------------------------------------------------
__global__ __launch_bounds__(256) void pass2_kernel(
    const int4* __restrict__ staging, const int* __restrict__ rowptr,
    const float* __restrict__ mu1, const float* __restrict__ sg1,
    const float* __restrict__ mu2, const float* __restrict__ sg2,
    int4* __restrict__ rec, int N) {
    __shared__ int lcur[BKT_SIZE];
    int b = blockIdx.x;
    int node0 = b << BKT_SHIFT;
    int t = threadIdx.x;
    int nn = min(BKT_SIZE, N - node0);
    if (t < nn) lcur[t] = rowptr[node0 + t];
    __syncthreads();
    int beg = rowptr[node0];
    int end = rowptr[min(node0 + BKT_SIZE, N)];

    float m1x[3], m1y[3], i1x[3], i1y[3], m2x[3], m2y[3], i2x[3], i2y[3];
#pragma unroll
    for (int k = 0; k < 3; ++k) {
        m1x[k] = mu1[2 * k]; m1y[k] = mu1[2 * k + 1];
        float s0 = sg1[2 * k], s1 = sg1[2 * k + 1];
        i1x[k] = -0.5f / (EPS + s0 * s0); i1y[k] = -0.5f / (EPS + s1 * s1);
        m2x[k] = mu2[2 * k]; m2y[k] = mu2[2 * k + 1];
        s0 = sg2[2 * k]; s1 = sg2[2 * k + 1];
        i2x[k] = -0.5f / (EPS + s0 * s0); i2y[k] = -0.5f / (EPS + s1 * s1);
    }

    for (int j = beg + t; j < end; j += 256) {
        int4 p = staging[j];
        float ax = __int_as_float(p.z), ay = __int_as_float(p.w);
        float g1v[3], g2v[3];
#pragma unroll
        for (int k = 0; k < 3; ++k) {
            float d0 = ax - m1x[k], d1 = ay - m1y[k];
            g1v[k] = __expf(d0 * d0 * i1x[k] + d1 * d1 * i1y[k]);
            d0 = ax - m2x[k]; d1 = ay - m2y[k];
            g2v[k] = __expf(d0 * d0 * i2x[k] + d1 * d1 * i2y[k]);
        }
        int pos = atomicAdd(&lcur[p.y & (BKT_SIZE - 1)], 1);
        int4 r;
        r.x = p.x;
        r.y = h2_as_int(__floats2half2_rn(g1v[0], g1v[1]));
        r.z = h2_as_int(__floats2half2_rn(g1v[2], g2v[0]));
        r.w = h2_as_int(__floats2half2_rn(g2v[1], g2v[2]));
        rec[pos] = r;
    }
}

// ---------------------------------------------------------------------------
// Bprep: fragment-ordered fp16 copy of W = [g1 | r1]  (128 x 256).
// ---------------------------------------------------------------------------
__global__ void bprep_kernel(const float* __restrict__ g1, const float* __restrict__ r1,
                             __half* __restrict__ Bprep) {
    int gid = blockIdx.x * 256 + threadIdx.x;   // 32768 total
    if (gid >= 32768) return;
    int fi = gid >> 9;
    int lane = (gid >> 3) & 63;
    int i = gid & 7;
    int ks = fi & 3, cb = fi >> 2;
    int k = ks * 32 + (lane >> 4) * 8 + i;
    int c = cb * 16 + (lane & 15);
    float v = (c < 192) ? g1[k * 192 + c] : r1[k * 64 + (c - 192)];
    Bprep[gid] = __float2half(v);
}

// ---------------------------------------------------------------------------
// Layer-1 GEMM via MFMA f16: x [M,128] fp32 -> hw1h [M,256] fp16.
// ---------------------------------------------------------------------------
__global__ __launch_bounds__(256) void gemm1_mfma(
    const float* __restrict__ A, const __half* __restrict__ Bprep,
    __half* __restrict__ Cout, int M) {
    __shared__ char a_lds[128 * 256];
    int row0 = blockIdx.x * 128;
    int tid = threadIdx.x;

    {
        int r = tid >> 1;
        int kh = (tid & 1) * 64;
        int gr = row0 + r;
        bool valid = gr < M;
        const float4* src = reinterpret_cast<const float4*>(A + (size_t)gr * 128 + kh);
#pragma unroll
        for (int i = 0; i < 8; ++i) {
            float4 f0 = valid ? src[2 * i]     : make_float4(0.f, 0.f, 0.f, 0.f);
            float4 f1 = valid ? src[2 * i + 1] : make_float4(0.f, 0.f, 0.f, 0.f);
            int4 v;
            v.x = h2_as_int(__floats2half2_rn(f0.x, f0.y));
            v.y = h2_as_int(__floats2half2_rn(f0.z, f0.w));
            v.z = h2_as_int(__floats2half2_rn(f1.x, f1.y));
            v.w = h2_as_int(__floats2half2_rn(f1.z, f1.w));
            int byte = r * 256 + kh * 2 + i * 16;
            byte ^= (r & 7) << 4;
            *reinterpret_cast<int4*>(&a_lds[byte]) = v;
        }
    }

    int wid = tid >> 6, lane = tid & 63;
    int wr = wid & 1, wc = wid >> 1;

    v8h bf[4][4];
#pragma unroll
    for (int cf = 0; cf < 4; ++cf)
#pragma unroll
        for (int ks = 0; ks < 4; ++ks) {
            int cb = blockIdx.y * 8 + wc * 4 + cf;
            int fi = cb * 4 + ks;
            bf[cf][ks] = *reinterpret_cast<const v8h*>(Bprep + (size_t)fi * 512 + lane * 8);
        }

    __syncthreads();

    v4f acc[4][4] = {};
#pragma unroll
    for (int ks = 0; ks < 4; ++ks) {
        v8h af[4];
#pragma unroll
        for (int rf = 0; rf < 4; ++rf) {
            int r = wr * 64 + rf * 16 + (lane & 15);
            int byte = r * 256 + ks * 64 + (lane >> 4) * 16;
            byte ^= (r & 7) << 4;
            af[rf] = *reinterpret_cast<const v8h*>(&a_lds[byte]);
        }
#pragma unroll
        for (int rf = 0; rf < 4; ++rf)
#pragma unroll
            for (int cf = 0; cf < 4; ++cf)
                acc[rf][cf] = __builtin_amdgcn_mfma_f32_16x16x32_f16(
                    af[rf], bf[cf][ks], acc[rf][cf], 0, 0, 0);
    }

#pragma unroll
    for (int rf = 0; rf < 4; ++rf)
#pragma unroll
        for (int cf = 0; cf < 4; ++cf)
#pragma unroll
            for (int i = 0; i < 4; ++i) {
                int gr = row0 + wr * 64 + rf * 16 + (lane >> 4) * 4 + i;
                int gc = blockIdx.y * 128 + wc * 64 + cf * 16 + (lane & 15);
                if (gr < M) Cout[(size_t)gr * 256 + gc] = __float2half(acc[rf][cf][i]);
            }
}

// ---------------------------------------------------------------------------
// Vector GEMM (layer 2): Cout[n,c] = A[n,:] @ [W1|W2], fp16 out.
// ---------------------------------------------------------------------------
template<int K, int TN, int TC, int C1, int C2>
__global__ __launch_bounds__(256) void gemm_cat(
    const float* __restrict__ A, const float* __restrict__ W1,
    const float* __restrict__ W2, __half* __restrict__ Cout, int nrows) {
    constexpr int NT = TN / 8;
    constexpr int CT = TC / 4;
    static_assert(NT * CT == 256, "bad tile");
    constexpr int COLS = C1 + C2;
    __shared__ float xs[TN][K + 4];

    int row0 = blockIdx.x * TN;
    int col0 = blockIdx.y * TC;

    constexpr int NV = TN * (K / 4);
    for (int id = threadIdx.x; id < NV; id += 256) {
        int r  = id / (K / 4);
        int k4 = id % (K / 4);
        int gr = row0 + r;
        float4 v = make_float4(0.f, 0.f, 0.f, 0.f);
        if (gr < nrows) v = reinterpret_cast<const float4*>(A + (size_t)gr * K)[k4];
        *reinterpret_cast<float4*>(&xs[r][4 * k4]) = v;
    }
    __syncthreads();

    int ct = threadIdx.x % CT;
    int nt = threadIdx.x / CT;
    int c0 = col0 + ct * 4;

    const float* wp;
    int wstride;
    if (c0 < C1) { wp = W1 + c0;        wstride = C1; }
    else         { wp = W2 + (c0 - C1); wstride = C2; }

    float acc[8][4] = {};
#pragma unroll 4
    for (int k = 0; k < K; ++k) {
        float4 w = *reinterpret_cast<const float4*>(wp + (size_t)k * wstride);
        float xr[8];
#pragma unroll
        for (int i = 0; i < 8; ++i) xr[i] = xs[nt * 8 + i][k];
#pragma unroll
        for (int i = 0; i < 8; ++i) {
            acc[i][0] += xr[i] * w.x;
            acc[i][1] += xr[i] * w.y;
            acc[i][2] += xr[i] * w.z;
            acc[i][3] += xr[i] * w.w;
        }
    }

#pragma unroll
    for (int i = 0; i < 8; ++i) {
        int gr = row0 + nt * 8 + i;
        if (gr < nrows) {
            __half2* p = reinterpret_cast<__half2*>(Cout + (size_t)gr * COLS + c0);
            p[0] = __floats2half2_rn(acc[i][0], acc[i][1]);
            p[1] = __floats2half2_rn(acc[i][2], acc[i][3]);
        }
    }
}

// ---------------------------------------------------------------------------
// agg1: 32 lanes per node, lane owns m = {2l, 2l+1} via half2.
// ---------------------------------------------------------------------------
__global__ __launch_bounds__(256) void agg1_kernel(
    const int4* __restrict__ rec, const int* __restrict__ rowptr,
    const __half* __restrict__ hw1h, const float* __restrict__ b1,
    float* __restrict__ h2, int N) {
    int node = (blockIdx.x * 256 + threadIdx.x) >> 5;
    int l = threadIdx.x & 31;
    if (node >= N) return;
    int beg = rowptr[node], end = rowptr[node + 1];
    float ax0 = 0.f, ay0 = 0.f, ax1 = 0.f, ay1 = 0.f;
    int j = beg;
    for (; j + 1 < end; j += 2) {
        int4 r0 = rec[j], r1 = rec[j + 1];
        __half2 ha0 = int_as_h2(r0.y), hb0 = int_as_h2(r0.z);
        __half2 ha1 = int_as_h2(r1.y), hb1 = int_as_h2(r1.z);
        float g00 = __low2float(ha0), g01 = __high2float(ha0), g02 = __low2float(hb0);
        float g10 = __low2float(ha1), g11 = __high2float(ha1), g12 = __low2float(hb1);
        const __half2* p0 = reinterpret_cast<const __half2*>(hw1h + (size_t)r0.x * 256);
        const __half2* p1 = reinterpret_cast<const __half2*>(hw1h + (size_t)r1.x * 256);
        float2 f00 = __half22float2(p0[l]);
        float2 f01 = __half22float2(p0[32 + l]);
        float2 f02 = __half22float2(p0[64 + l]);
        float2 f10 = __half22float2(p1[l]);
        float2 f11 = __half22float2(p1[32 + l]);
        float2 f12 = __half22float2(p1[64 + l]);
        ax0 += g00 * f00.x + g01 * f01.x + g02 * f02.x;
        ay0 += g00 * f00.y + g01 * f01.y + g02 * f02.y;
        ax1 += g10 * f10.x + g11 * f11.x + g12 * f12.x;
        ay1 += g10 * f10.y + g11 * f11.y + g12 * f12.y;
    }
    if (j < end) {
        int4 r0 = rec[j];
        __half2 ha0 = int_as_h2(r0.y), hb0 = int_as_h2(r0.z);
        float g00 = __low2float(ha0), g01 = __high2float(ha0), g02 = __low2float(hb0);
        const __half2* p0 = reinterpret_cast<const __half2*>(hw1h + (size_t)r0.x * 256);
        float2 f00 = __half22float2(p0[l]);
        float2 f01 = __half22float2(p0[32 + l]);
        float2 f02 = __half22float2(p0[64 + l]);
        ax0 += g00 * f00.x + g01 * f01.x + g02 * f02.x;
        ay0 += g00 * f00.y + g01 * f01.y + g02 * f02.y;
    }
    float d = fmaxf((float)(end - beg), 1.0f);
    float2 root = __half22float2(
        reinterpret_cast<const __half2*>(hw1h + (size_t)node * 256 + 192)[l]);
    float2 bb = reinterpret_cast<const float2*>(b1)[l];
    float v0 = (ax0 + ax1) / d + root.x + bb.x;
    float v1 = (ay0 + ay1) / d + root.y + bb.y;
    float2 o;
    o.x = v0 > 0.f ? v0 : expm1f(v0);
    o.y = v1 > 0.f ? v1 : expm1f(v1);
    reinterpret_cast<float2*>(h2 + (size_t)node * 64)[l] = o;
}

// ---------------------------------------------------------------------------
// agg2: 8 lanes per node, lane owns c = {2l, 2l+1} via half2.
// ---------------------------------------------------------------------------
__global__ __launch_bounds__(256) void agg2_kernel(
    const int4* __restrict__ rec, const int* __restrict__ rowptr,
    const __half* __restrict__ hw2h, const float* __restrict__ b2,
    float* __restrict__ out, int N) {
    int node = (blockIdx.x * 256 + threadIdx.x) >> 3;
    int l = threadIdx.x & 7;
    if (node >= N) return;
    int beg = rowptr[node], end = rowptr[node + 1];
    float ax = 0.f, ay = 0.f;
    for (int j = beg; j < end; ++j) {
        int4 r = rec[j];
        __half2 hb = int_as_h2(r.z), hc = int_as_h2(r.w);
        float g0 = __high2float(hb), g1 = __low2float(hc), g2 = __high2float(hc);
        const __half2* p = reinterpret_cast<const __half2*>(hw2h + (size_t)r.x * 64);
        float2 f0 = __half22float2(p[l]);
        float2 f1 = __half22float2(p[8 + l]);
        float2 f2 = __half22float2(p[16 + l]);
        ax += g0 * f0.x + g1 * f1.x + g2 * f2.x;
        ay += g0 * f0.y + g1 * f1.y + g2 * f2.y;
    }
    float d = fmaxf((float)(end - beg), 1.0f);
    float2 root = __half22float2(
        reinterpret_cast<const __half2*>(hw2h + (size_t)node * 64 + 48)[l]);
    float2 bb = reinterpret_cast<const float2*>(b2)[l];
    float v0 = ax / d + root.x + bb.x;
    float v1 = ay / d + root.y + bb.y;

    float mx = fmaxf(v0, v1);
#pragma unroll
    for (int off = 4; off >= 1; off >>= 1) mx = fmaxf(mx, __shfl_xor(mx, off, 8));
    float s = __expf(v0 - mx) + __expf(v1 - mx);
#pragma unroll
    for (int off = 4; off >= 1; off >>= 1) s += __shfl_xor(s, off, 8);
    float ls = __logf(s);
    float2 o = make_float2(v0 - mx - ls, v1 - mx - ls);
    reinterpret_cast<float2*>(out + (size_t)node * 16)[l] = o;
}

// ---------------------------------------------------------------------------
extern "C" void kernel_launch(void* const* d_in, const int* in_sizes, int n_in,
                              void* d_out, int out_size, void* d_ws, size_t ws_size,
                              hipStream_t stream) {
    const float* x   = (const float*)d_in[0];
    const int*   ei  = (const int*)d_in[1];
    const float* ea  = (const float*)d_in[2];
    const float* g1  = (const float*)d_in[3];
    const float* mu1 = (const float*)d_in[4];
    const float* sg1 = (const float*)d_in[5];
    const float* r1  = (const float*)d_in[6];
    const float* b1  = (const float*)d_in[7];
    const float* g2  = (const float*)d_in[8];
    const float* mu2 = (const float*)d_in[9];
    const float* sg2 = (const float*)d_in[10];
    const float* r2  = (const float*)d_in[11];
    const float* b2  = (const float*)d_in[12];

    const int N = in_sizes[0] / 128;   // 50000
    const int E = in_sizes[2] / 2;     // 800000
    const int NB = (N + 255) / 256;
    const int nbkt = (N + BKT_SIZE - 1) >> BKT_SHIFT;   // 391

    // Workspace layout
    __half* hw1h = (__half*)d_ws;                         // N*256 halves (25.6MB)
    float*  h2   = (float*)(hw1h + (size_t)N * 256);      // N*64 fp32
    __half* hw2h = (__half*)(h2 + (size_t)N * 64);        // N*64 halves
    int4*   rec  = (int4*)(hw2h + (size_t)N * 64);        // E int4 (12.8MB)
    int4*   staging = rec + E;                            // E int4 (12.8MB)
    __half* Bprep = (__half*)(staging + E);               // 32768 halves
    int*    deg    = (int*)(Bprep + 32768);               // N
    int*    rowptr = deg + N;                             // N+1
    int*    bcursor = rowptr + N + 1;                     // nbkt
    int*    bsum   = bcursor + nbkt;                      // 256
    int*    flag   = bsum + 256;                          // 1

    hipMemsetAsync(deg, 0, sizeof(int) * N, stream);

    detect_kernel<<<1, 256, 0, stream>>>(ei, flag);
    hist_kernel<<<(E + 255) / 256, 256, 0, stream>>>(ei, flag, deg, E);
    scan_part<<<NB, 256, 0, stream>>>(deg, bsum, N);
    scan_base<<<1, 256, 0, stream>>>(bsum, NB, rowptr + N, E);
    scan_final<<<NB, 256, 0, stream>>>(deg, bsum, rowptr, N);
    bkt_init<<<(nbkt + 255) / 256, 256, 0, stream>>>(rowptr, bcursor, nbkt);

    pass1_kernel<<<(E + 1023) / 1024, 256, 0, stream>>>(
        ei, flag, (const float2*)ea, bcursor, staging, E, nbkt);
    pass2_kernel<<<nbkt, 256, 0, stream>>>(
        staging, rowptr, mu1, sg1, mu2, sg2, rec, N);

    // Layer 1 GEMM (MFMA): x [N,128] @ [g1|root1] -> hw1h fp16 [N,256]
    bprep_kernel<<<128, 256, 0, stream>>>(g1, r1, Bprep);
    gemm1_mfma<<<dim3((N + 127) / 128, 2), 256, 0, stream>>>(x, Bprep, hw1h, N);

    agg1_kernel<<<((size_t)N * 32 + 255) / 256, 256, 0, stream>>>(
        rec, rowptr, hw1h, b1, h2, N);

    // Layer 2 GEMM: h2 [N,64] @ [g2|root2] [64,64] -> hw2h (fp16)
    gemm_cat<64, 128, 64, 48, 16>
        <<<dim3((N + 127) / 128, 1), 256, 0, stream>>>(h2, g2, r2, hw2h, N);

    agg2_kernel<<<((size_t)N * 8 + 255) / 256, 256, 0, stream>>>(
        rec, rowptr, hw2h, b2, (float*)d_out, N);
}